// Round 10
// baseline (204.305 us; speedup 1.0000x reference)
//
#include <hip/hip_runtime.h>
#include <hip/hip_bf16.h>

#define E_EDGES 1000000
#define N_NODES 100000
#define HDIM 128
#define BM 64
#define LDP 136   // padded LDS row stride for bf16 tiles
#define REC 384   // shorts per node record: [x_bf(128) | A(128) | B(128)]

typedef __attribute__((ext_vector_type(8))) short short8;
typedef __attribute__((ext_vector_type(4))) float f32x4;

static __device__ __forceinline__ short f2bf(float f) {
  unsigned int u = __float_as_uint(f);
  unsigned int r = (u + 0x7FFFu + ((u >> 16) & 1u)) >> 16;
  return (short)r;
}
static __device__ __forceinline__ float bf2f(short s) {
  return __uint_as_float(((unsigned int)(unsigned short)s) << 16);
}
static __device__ __forceinline__ unsigned int bfsub_abs2(unsigned int a, unsigned int b) {
  __hip_bfloat162 x, y;
  __builtin_memcpy(&x, &a, 4);
  __builtin_memcpy(&y, &b, 4);
  __hip_bfloat162 r = __habs2(__hsub2(x, y));
  unsigned int u;
  __builtin_memcpy(&u, &r, 4);
  return u;
}
static __device__ __forceinline__ unsigned int bfadd2(unsigned int a, unsigned int b) {
  __hip_bfloat162 x, y;
  __builtin_memcpy(&x, &a, 4);
  __builtin_memcpy(&y, &b, 4);
  __hip_bfloat162 r = __hadd2(x, y);
  unsigned int u;
  __builtin_memcpy(&u, &r, 4);
  return u;
}

// ---- k0: transpose + bf16-ize weights: Wt[out][in] row-major ----
__global__ void prep_weights(const float* __restrict__ Wp, const float* __restrict__ Wc,
                             const float* __restrict__ W1, const float* __restrict__ W2,
                             short* __restrict__ wp_t, short* __restrict__ wc_t,
                             short* __restrict__ w1_t, float* __restrict__ w2v) {
  int i = blockIdx.x * 256 + threadIdx.x;
  if (i < HDIM * HDIM) {
    int o = i >> 7, k = i & (HDIM - 1);
    wp_t[i] = f2bf(Wp[k * HDIM + o]);
    wc_t[i] = f2bf(Wc[k * HDIM + o]);
  }
  if (i < HDIM * 3 * HDIM) {
    int o = i / (3 * HDIM), k = i - o * (3 * HDIM);
    w1_t[i] = f2bf(W1[k * HDIM + o]);
  }
  if (i < HDIM) w2v[i] = W2[i];
}

// ---- k1: per-node precompute into interleaved records ----
// LDS-frugal: 2 buffers (Yc reuses Xt space); coalesced rec writes via LDS staging.
__global__ __launch_bounds__(256) void node_precompute(
    const float* __restrict__ x, const float* __restrict__ b_p,
    const float* __restrict__ b_c, const float* __restrict__ b1,
    const short* __restrict__ wp_t, const short* __restrict__ wc_t,
    const short* __restrict__ w1_t, short* __restrict__ rec) {
  __shared__ __align__(16) short Buf1[BM * LDP];  // Xt, then Yc, then B-stage
  __shared__ __align__(16) short Buf2[BM * LDP];  // Yp, then A-stage

  const int t = threadIdx.x;
  const int n0 = blockIdx.x * BM;
  const int lane16 = t & 15, rq = t >> 4, c0 = lane16 * 8;

  // Phase A: stage x -> Buf1 (Xt); write x_bf part of rec (coalesced)
#pragma unroll
  for (int pass = 0; pass < 4; ++pass) {
    const int row = pass * 16 + rq;
    const int n = n0 + row;
    short8 v;
    if (n < N_NODES) {
      const float* ps = x + (size_t)n * HDIM + c0;
      float4 a = *(const float4*)ps;
      float4 b = *(const float4*)(ps + 4);
      float f[8] = {a.x, a.y, a.z, a.w, b.x, b.y, b.z, b.w};
#pragma unroll
      for (int j = 0; j < 8; ++j) v[j] = f2bf(f[j]);
      *(short8*)&rec[(size_t)n * REC + c0] = v;
    } else {
#pragma unroll
      for (int j = 0; j < 8; ++j) v[j] = 0;
    }
    *(short8*)&Buf1[row * LDP + c0] = v;
  }
  __syncthreads();

  const int l = t & 63;
  const int w = t >> 6;
  const int lr = l & 15;
  const int lg = l >> 4;
  const int aoff = lr * LDP + lg * 8;
  const int na = w * 32 + lr, nb = na + 16;

  const f32x4 zero4 = {0.f, 0.f, 0.f, 0.f};
  f32x4 ap_[4][2], ac_[4][2];
#pragma unroll
  for (int mi = 0; mi < 4; ++mi) {
    ap_[mi][0] = zero4; ap_[mi][1] = zero4;
    ac_[mi][0] = zero4; ac_[mi][1] = zero4;
  }

  const short* wpA = wp_t + na * HDIM + lg * 8;
  const short* wpB = wp_t + nb * HDIM + lg * 8;
  const short* wcA = wc_t + na * HDIM + lg * 8;
  const short* wcB = wc_t + nb * HDIM + lg * 8;

  // Phase B: GEMM1/2 from Buf1(Xt)
#pragma unroll
  for (int kk = 0; kk < 4; ++kk) {
    short8 b10 = *(const short8*)(wpA + kk * 32);
    short8 b11 = *(const short8*)(wpB + kk * 32);
    short8 b20 = *(const short8*)(wcA + kk * 32);
    short8 b21 = *(const short8*)(wcB + kk * 32);
#pragma unroll
    for (int mi = 0; mi < 4; ++mi) {
      short8 a8 = *(const short8*)&Buf1[mi * 16 * LDP + aoff + kk * 32];
      ap_[mi][0] = __builtin_amdgcn_mfma_f32_16x16x32_bf16(a8, b10, ap_[mi][0], 0, 0, 0);
      ap_[mi][1] = __builtin_amdgcn_mfma_f32_16x16x32_bf16(a8, b11, ap_[mi][1], 0, 0, 0);
      ac_[mi][0] = __builtin_amdgcn_mfma_f32_16x16x32_bf16(a8, b20, ac_[mi][0], 0, 0, 0);
      ac_[mi][1] = __builtin_amdgcn_mfma_f32_16x16x32_bf16(a8, b21, ac_[mi][1], 0, 0, 0);
    }
  }
  __syncthreads();  // all Xt reads done; Buf1 can be overwritten

  // lrelu+bias: Yp -> Buf2, Yc -> Buf1
  {
    const float bpa = b_p[na], bpb = b_p[nb];
    const float bca = b_c[na], bcb = b_c[nb];
#pragma unroll
    for (int mi = 0; mi < 4; ++mi) {
#pragma unroll
      for (int r = 0; r < 4; ++r) {
        const int m = mi * 16 + lg * 4 + r;
        float v0 = ap_[mi][0][r] + bpa; v0 = v0 > 0.f ? v0 : 0.01f * v0;
        float v1 = ap_[mi][1][r] + bpb; v1 = v1 > 0.f ? v1 : 0.01f * v1;
        float u0 = ac_[mi][0][r] + bca; u0 = u0 > 0.f ? u0 : 0.01f * u0;
        float u1 = ac_[mi][1][r] + bcb; u1 = u1 > 0.f ? u1 : 0.01f * u1;
        Buf2[m * LDP + na] = f2bf(v0);
        Buf2[m * LDP + nb] = f2bf(v1);
        Buf1[m * LDP + na] = f2bf(u0);
        Buf1[m * LDP + nb] = f2bf(u1);
      }
    }
  }
  __syncthreads();

  // Phase C: GEMM3a (Buf2=Yp @ W1a), GEMM3b (Buf1=Yc @ W1b)
  f32x4 aa_[4][2], ab_[4][2];
#pragma unroll
  for (int mi = 0; mi < 4; ++mi) {
    aa_[mi][0] = zero4; aa_[mi][1] = zero4;
    ab_[mi][0] = zero4; ab_[mi][1] = zero4;
  }
  const short* w1Aa = w1_t + na * (3 * HDIM) + lg * 8;
  const short* w1Ab = w1_t + nb * (3 * HDIM) + lg * 8;
#pragma unroll
  for (int kk = 0; kk < 4; ++kk) {
    short8 ba0 = *(const short8*)(w1Aa + kk * 32);
    short8 ba1 = *(const short8*)(w1Ab + kk * 32);
    short8 bb0 = *(const short8*)(w1Aa + HDIM + kk * 32);
    short8 bb1 = *(const short8*)(w1Ab + HDIM + kk * 32);
#pragma unroll
    for (int mi = 0; mi < 4; ++mi) {
      short8 ayp = *(const short8*)&Buf2[mi * 16 * LDP + aoff + kk * 32];
      short8 ayc = *(const short8*)&Buf1[mi * 16 * LDP + aoff + kk * 32];
      aa_[mi][0] = __builtin_amdgcn_mfma_f32_16x16x32_bf16(ayp, ba0, aa_[mi][0], 0, 0, 0);
      aa_[mi][1] = __builtin_amdgcn_mfma_f32_16x16x32_bf16(ayp, ba1, aa_[mi][1], 0, 0, 0);
      ab_[mi][0] = __builtin_amdgcn_mfma_f32_16x16x32_bf16(ayc, bb0, ab_[mi][0], 0, 0, 0);
      ab_[mi][1] = __builtin_amdgcn_mfma_f32_16x16x32_bf16(ayc, bb1, ab_[mi][1], 0, 0, 0);
    }
  }
  __syncthreads();  // Yp/Yc reads done; buffers reusable for output staging

  // Stage A -> Buf2, B -> Buf1 as [node][col], then coalesced store
  {
    const float b1a = b1[na], b1b = b1[nb];
#pragma unroll
    for (int mi = 0; mi < 4; ++mi) {
#pragma unroll
      for (int r = 0; r < 4; ++r) {
        const int m = mi * 16 + lg * 4 + r;
        Buf2[m * LDP + na] = f2bf(aa_[mi][0][r] + b1a);
        Buf2[m * LDP + nb] = f2bf(aa_[mi][1][r] + b1b);
        Buf1[m * LDP + na] = f2bf(ab_[mi][0][r]);
        Buf1[m * LDP + nb] = f2bf(ab_[mi][1][r]);
      }
    }
  }
  __syncthreads();

#pragma unroll
  for (int pass = 0; pass < 4; ++pass) {
    const int row = pass * 16 + rq;
    const int n = n0 + row;
    if (n < N_NODES) {
      short* rn = rec + (size_t)n * REC;
      *(short8*)&rn[HDIM + c0] = *(const short8*)&Buf2[row * LDP + c0];
      *(short8*)&rn[2 * HDIM + c0] = *(const short8*)&Buf1[row * LDP + c0];
    }
  }
}

// ---- k2: per-edge, 2 tiles/block with register prefetch (T14) ----
__global__ __launch_bounds__(512, 6) void edge_kernel(
    const int* __restrict__ ei, const short* __restrict__ rec,
    const short* __restrict__ w1_t, const float* __restrict__ w2v,
    const float* __restrict__ b2, float* __restrict__ out) {
  __shared__ __align__(16) short Dt[BM * LDP];
  __shared__ __align__(16) short St[BM * LDP];
  __shared__ float partial[8][BM];

  const int t = threadIdx.x;
  const int lane16 = t & 15, rq = t >> 4, c0 = lane16 * 8;
  const int e0A = blockIdx.x * 2 * BM;
  const int e0B = e0A + BM;
  const bool hasB = (e0B < E_EDGES);

  const int l = t & 63;
  const int w = t >> 6;
  const int lr = l & 15;
  const int lg = l >> 4;
  const int aoff = lr * LDP + lg * 8;
  const int na = w * 16 + lr;
  const int scol = w * 16 + lg * 4;
  const short* w1D = w1_t + na * (3 * HDIM) + 2 * HDIM + lg * 8;
  const float4 w2q = *(const float4*)&w2v[w * 16 + lg * 4];

  // ---- issue tile-A gathers (and tile-B indices) ----
  const int rowLo = rq, rowHi = 32 + rq;
  int sA0 = ei[e0A + rowLo], dA0 = ei[E_EDGES + e0A + rowLo];
  int sA1 = ei[e0A + rowHi], dA1 = ei[E_EDGES + e0A + rowHi];
  int sB0 = 0, dB0 = 0, sB1 = 0, dB1 = 0;
  if (hasB) {
    sB0 = ei[e0B + rowLo]; dB0 = ei[E_EDGES + e0B + rowLo];
    sB1 = ei[e0B + rowHi]; dB1 = ei[E_EDGES + e0B + rowHi];
  }
  const short* rsA0 = rec + (size_t)sA0 * REC + c0;
  const short* rdA0 = rec + (size_t)dA0 * REC + c0;
  const short* rsA1 = rec + (size_t)sA1 * REC + c0;
  const short* rdA1 = rec + (size_t)dA1 * REC + c0;
  uint4 pA0 = *(const uint4*)rsA0, aA0 = *(const uint4*)(rsA0 + HDIM);
  uint4 cA0 = *(const uint4*)rdA0, bA0 = *(const uint4*)(rdA0 + 2 * HDIM);
  uint4 pA1 = *(const uint4*)rsA1, aA1 = *(const uint4*)(rsA1 + HDIM);
  uint4 cA1 = *(const uint4*)rdA1, bA1 = *(const uint4*)(rdA1 + 2 * HDIM);

  // ---- pack tile A -> LDS ----
  {
    uint4 vd, vs;
    vd.x = bfsub_abs2(pA0.x, cA0.x); vd.y = bfsub_abs2(pA0.y, cA0.y);
    vd.z = bfsub_abs2(pA0.z, cA0.z); vd.w = bfsub_abs2(pA0.w, cA0.w);
    vs.x = bfadd2(aA0.x, bA0.x); vs.y = bfadd2(aA0.y, bA0.y);
    vs.z = bfadd2(aA0.z, bA0.z); vs.w = bfadd2(aA0.w, bA0.w);
    *(uint4*)&Dt[rowLo * LDP + c0] = vd;
    *(uint4*)&St[rowLo * LDP + c0] = vs;
    vd.x = bfsub_abs2(pA1.x, cA1.x); vd.y = bfsub_abs2(pA1.y, cA1.y);
    vd.z = bfsub_abs2(pA1.z, cA1.z); vd.w = bfsub_abs2(pA1.w, cA1.w);
    vs.x = bfadd2(aA1.x, bA1.x); vs.y = bfadd2(aA1.y, bA1.y);
    vs.z = bfadd2(aA1.z, bA1.z); vs.w = bfadd2(aA1.w, bA1.w);
    *(uint4*)&Dt[rowHi * LDP + c0] = vd;
    *(uint4*)&St[rowHi * LDP + c0] = vs;
  }

  // ---- issue tile-B gathers (in flight across tile-A compute) ----
  uint4 pB0, aB0, cB0, bB0, pB1, aB1, cB1, bB1;
  if (hasB) {
    const short* rsB0 = rec + (size_t)sB0 * REC + c0;
    const short* rdB0 = rec + (size_t)dB0 * REC + c0;
    const short* rsB1 = rec + (size_t)sB1 * REC + c0;
    const short* rdB1 = rec + (size_t)dB1 * REC + c0;
    pB0 = *(const uint4*)rsB0; aB0 = *(const uint4*)(rsB0 + HDIM);
    cB0 = *(const uint4*)rdB0; bB0 = *(const uint4*)(rdB0 + 2 * HDIM);
    pB1 = *(const uint4*)rsB1; aB1 = *(const uint4*)(rsB1 + HDIM);
    cB1 = *(const uint4*)rdB1; bB1 = *(const uint4*)(rdB1 + 2 * HDIM);
  }
  __syncthreads();

  // ---- compute tile (LDS -> MFMA -> partial -> out) ----
  auto do_tile = [&](int ebase) {
    f32x4 acc[4];
#pragma unroll
    for (int mi = 0; mi < 4; ++mi) {
      uint2 u = *(const uint2*)&St[(mi * 16 + lr) * LDP + scol];
      acc[mi][0] = __uint_as_float(u.x << 16);
      acc[mi][1] = __uint_as_float(u.x & 0xffff0000u);
      acc[mi][2] = __uint_as_float(u.y << 16);
      acc[mi][3] = __uint_as_float(u.y & 0xffff0000u);
    }
#pragma unroll
    for (int kk = 0; kk < 4; ++kk) {
      short8 b8 = *(const short8*)(w1D + kk * 32);
#pragma unroll
      for (int mi = 0; mi < 4; ++mi) {
        short8 a8 = *(const short8*)&Dt[mi * 16 * LDP + aoff + kk * 32];
        acc[mi] = __builtin_amdgcn_mfma_f32_16x16x32_bf16(b8, a8, acc[mi], 0, 0, 0);
      }
    }
#pragma unroll
    for (int mi = 0; mi < 4; ++mi) {
      float p = fmaxf(acc[mi][0], 0.f) * w2q.x + fmaxf(acc[mi][1], 0.f) * w2q.y +
                fmaxf(acc[mi][2], 0.f) * w2q.z + fmaxf(acc[mi][3], 0.f) * w2q.w;
      p += __shfl_xor(p, 16);
      p += __shfl_xor(p, 32);
      if (lg == 0) partial[w][mi * 16 + lr] = p;
    }
    __syncthreads();  // partial ready; also: all Dt/St reads complete
    if (t < BM) {
      float z = partial[0][t] + partial[1][t] + partial[2][t] + partial[3][t] +
                partial[4][t] + partial[5][t] + partial[6][t] + partial[7][t] + b2[0];
      out[ebase + t] = 1.0f / (1.0f + __expf(-z));
    }
  };

  do_tile(e0A);

  if (hasB) {
    // pack tile B -> LDS (safe: post-barrier, tile-A LDS reads done)
    uint4 vd, vs;
    vd.x = bfsub_abs2(pB0.x, cB0.x); vd.y = bfsub_abs2(pB0.y, cB0.y);
    vd.z = bfsub_abs2(pB0.z, cB0.z); vd.w = bfsub_abs2(pB0.w, cB0.w);
    vs.x = bfadd2(aB0.x, bB0.x); vs.y = bfadd2(aB0.y, bB0.y);
    vs.z = bfadd2(aB0.z, bB0.z); vs.w = bfadd2(aB0.w, bB0.w);
    *(uint4*)&Dt[rowLo * LDP + c0] = vd;
    *(uint4*)&St[rowLo * LDP + c0] = vs;
    vd.x = bfsub_abs2(pB1.x, cB1.x); vd.y = bfsub_abs2(pB1.y, cB1.y);
    vd.z = bfsub_abs2(pB1.z, cB1.z); vd.w = bfsub_abs2(pB1.w, cB1.w);
    vs.x = bfadd2(aB1.x, bB1.x); vs.y = bfadd2(aB1.y, bB1.y);
    vs.z = bfadd2(aB1.z, bB1.z); vs.w = bfadd2(aB1.w, bB1.w);
    *(uint4*)&Dt[rowHi * LDP + c0] = vd;
    *(uint4*)&St[rowHi * LDP + c0] = vs;
    __syncthreads();
    do_tile(e0B);
  }
}

// ---- fallback (validated v2 path) if workspace is too small ----
__global__ __launch_bounds__(512, 4) void edge_weight_fallback(
    const float* __restrict__ x, const int* __restrict__ ei,
    const float* __restrict__ b_p, const float* __restrict__ b_c,
    const float* __restrict__ b1, const float* __restrict__ b2,
    const short* __restrict__ wp_t, const short* __restrict__ wc_t,
    const short* __restrict__ w1_t, const float* __restrict__ w2v,
    float* __restrict__ out) {
  __shared__ __align__(16) short Pt[BM * LDP];
  __shared__ __align__(16) short Ct[BM * LDP];
  __shared__ __align__(16) short Dt[BM * LDP];
  __shared__ float partial[8][BM];

  const int t = threadIdx.x;
  const int e0 = blockIdx.x * BM;
  {
    const int lane16 = t & 15, rq = t >> 4, c0 = lane16 * 8;
#pragma unroll
    for (int pass = 0; pass < 2; ++pass) {
      const int row = pass * 32 + rq;
      const int ip = ei[e0 + row];
      const int ic = ei[E_EDGES + e0 + row];
      const float* ps = x + (size_t)ip * HDIM + c0;
      const float* cs = x + (size_t)ic * HDIM + c0;
      float4 pa = *(const float4*)ps, pb = *(const float4*)(ps + 4);
      float4 ca = *(const float4*)cs, cb = *(const float4*)(cs + 4);
      float pf[8] = {pa.x, pa.y, pa.z, pa.w, pb.x, pb.y, pb.z, pb.w};
      float cf[8] = {ca.x, ca.y, ca.z, ca.w, cb.x, cb.y, cb.z, cb.w};
      short8 vp, vc, vd;
#pragma unroll
      for (int j = 0; j < 8; ++j) {
        vp[j] = f2bf(pf[j]); vc[j] = f2bf(cf[j]); vd[j] = f2bf(fabsf(pf[j] - cf[j]));
      }
      *(short8*)&Pt[row * LDP + c0] = vp;
      *(short8*)&Ct[row * LDP + c0] = vc;
      *(short8*)&Dt[row * LDP + c0] = vd;
    }
  }
  __syncthreads();
  const int l = t & 63, w = t >> 6, lr = l & 15, lg = l >> 4;
  const int n0 = w * 16, na = n0 + lr, aoff = lr * LDP + lg * 8;
  const f32x4 zero4 = {0.f, 0.f, 0.f, 0.f};
  f32x4 acc1[4], acc2[4], acc3[4];
#pragma unroll
  for (int mi = 0; mi < 4; ++mi) { acc1[mi] = zero4; acc2[mi] = zero4; acc3[mi] = zero4; }
  const short* wpA = wp_t + na * HDIM + lg * 8;
  const short* wcA = wc_t + na * HDIM + lg * 8;
  const short* w1A = w1_t + na * (3 * HDIM) + lg * 8;
#pragma unroll
  for (int kk = 0; kk < 4; ++kk) {
    short8 bp8 = *(const short8*)(wpA + kk * 32);
    short8 bc8 = *(const short8*)(wcA + kk * 32);
    short8 bd8 = *(const short8*)(w1A + 2 * HDIM + kk * 32);
#pragma unroll
    for (int mi = 0; mi < 4; ++mi) {
      short8 ap = *(const short8*)&Pt[mi * 16 * LDP + aoff + kk * 32];
      short8 ac = *(const short8*)&Ct[mi * 16 * LDP + aoff + kk * 32];
      short8 ad = *(const short8*)&Dt[mi * 16 * LDP + aoff + kk * 32];
      acc1[mi] = __builtin_amdgcn_mfma_f32_16x16x32_bf16(ap, bp8, acc1[mi], 0, 0, 0);
      acc2[mi] = __builtin_amdgcn_mfma_f32_16x16x32_bf16(ac, bc8, acc2[mi], 0, 0, 0);
      acc3[mi] = __builtin_amdgcn_mfma_f32_16x16x32_bf16(ad, bd8, acc3[mi], 0, 0, 0);
    }
  }
  __syncthreads();
  {
    const float bpa = b_p[na], bca = b_c[na];
#pragma unroll
    for (int mi = 0; mi < 4; ++mi) {
#pragma unroll
      for (int r = 0; r < 4; ++r) {
        const int m = mi * 16 + lg * 4 + r;
        float v0 = acc1[mi][r] + bpa; v0 = v0 > 0.f ? v0 : 0.01f * v0;
        float u0 = acc2[mi][r] + bca; u0 = u0 > 0.f ? u0 : 0.01f * u0;
        Pt[m * LDP + na] = f2bf(v0);
        Ct[m * LDP + na] = f2bf(u0);
      }
    }
  }
  __syncthreads();
#pragma unroll
  for (int kk = 0; kk < 4; ++kk) {
    short8 b0 = *(const short8*)(w1A + kk * 32);
    short8 b1f = *(const short8*)(w1A + HDIM + kk * 32);
#pragma unroll
    for (int mi = 0; mi < 4; ++mi) {
      short8 a0 = *(const short8*)&Pt[mi * 16 * LDP + aoff + kk * 32];
      short8 a1 = *(const short8*)&Ct[mi * 16 * LDP + aoff + kk * 32];
      acc3[mi] = __builtin_amdgcn_mfma_f32_16x16x32_bf16(a0, b0, acc3[mi], 0, 0, 0);
      acc3[mi] = __builtin_amdgcn_mfma_f32_16x16x32_bf16(a1, b1f, acc3[mi], 0, 0, 0);
    }
  }
  {
    const float b1a = b1[na], w2a = w2v[na];
#pragma unroll
    for (int mi = 0; mi < 4; ++mi) {
#pragma unroll
      for (int r = 0; r < 4; ++r) {
        float h0 = acc3[mi][r] + b1a; h0 = h0 > 0.f ? h0 : 0.f;
        float v = h0 * w2a;
        v += __shfl_xor(v, 1); v += __shfl_xor(v, 2);
        v += __shfl_xor(v, 4); v += __shfl_xor(v, 8);
        if (lr == 0) partial[w][mi * 16 + lg * 4 + r] = v;
      }
    }
  }
  __syncthreads();
  if (t < BM) {
    float z = partial[0][t] + partial[1][t] + partial[2][t] + partial[3][t] +
              partial[4][t] + partial[5][t] + partial[6][t] + partial[7][t] + b2[0];
    out[e0 + t] = 1.0f / (1.0f + __expf(-z));
  }
}

extern "C" void kernel_launch(void* const* d_in, const int* in_sizes, int n_in,
                              void* d_out, int out_size, void* d_ws, size_t ws_size,
                              hipStream_t stream) {
  const float* x  = (const float*)d_in[0];
  const int*   ei = (const int*)d_in[1];
  const float* Wp = (const float*)d_in[2];
  const float* bp = (const float*)d_in[3];
  const float* Wc = (const float*)d_in[4];
  const float* bc = (const float*)d_in[5];
  const float* W1 = (const float*)d_in[6];
  const float* b1 = (const float*)d_in[7];
  const float* W2 = (const float*)d_in[8];
  const float* b2 = (const float*)d_in[9];
  float* out = (float*)d_out;

  short* wp_t = (short*)d_ws;
  short* wc_t = wp_t + HDIM * HDIM;
  short* w1_t = wc_t + HDIM * HDIM;
  float* w2v  = (float*)(w1_t + HDIM * 3 * HDIM);
  short* rec  = (short*)(w2v + HDIM);

  const size_t needed = (size_t)((char*)(rec + (size_t)N_NODES * REC) - (char*)d_ws);
  const int ntiles = E_EDGES / BM;

  prep_weights<<<(HDIM * 3 * HDIM + 255) / 256, 256, 0, stream>>>(Wp, Wc, W1, W2,
                                                                  wp_t, wc_t, w1_t, w2v);
  if (ws_size >= needed) {
    node_precompute<<<(N_NODES + BM - 1) / BM, 256, 0, stream>>>(
        x, bp, bc, b1, wp_t, wc_t, w1_t, rec);
    edge_kernel<<<(ntiles + 1) / 2, 512, 0, stream>>>(ei, rec, w1_t, w2v, b2, out);
  } else {
    edge_weight_fallback<<<ntiles, 512, 0, stream>>>(x, ei, bp, bc, b1, b2,
                                                     wp_t, wc_t, w1_t, w2v, out);
  }
}

// Round 11
// 193.589 us; speedup vs baseline: 1.0554x; 1.0554x over previous
//
#include <hip/hip_runtime.h>
#include <hip/hip_bf16.h>

#define E_EDGES 1000000
#define N_NODES 100000
#define HDIM 128
#define BM 64
#define LDP 136   // padded LDS row stride for bf16 tiles
#define REC 384   // shorts per node record: [x_bf(128) | A(128) | B(128)]

typedef __attribute__((ext_vector_type(8))) short short8;
typedef __attribute__((ext_vector_type(4))) float f32x4;

static __device__ __forceinline__ short f2bf(float f) {
  unsigned int u = __float_as_uint(f);
  unsigned int r = (u + 0x7FFFu + ((u >> 16) & 1u)) >> 16;
  return (short)r;
}
static __device__ __forceinline__ float bf2f(short s) {
  return __uint_as_float(((unsigned int)(unsigned short)s) << 16);
}
static __device__ __forceinline__ unsigned int bfsub_abs2(unsigned int a, unsigned int b) {
  __hip_bfloat162 x, y;
  __builtin_memcpy(&x, &a, 4);
  __builtin_memcpy(&y, &b, 4);
  __hip_bfloat162 r = __habs2(__hsub2(x, y));
  unsigned int u;
  __builtin_memcpy(&u, &r, 4);
  return u;
}
static __device__ __forceinline__ unsigned int bfadd2(unsigned int a, unsigned int b) {
  __hip_bfloat162 x, y;
  __builtin_memcpy(&x, &a, 4);
  __builtin_memcpy(&y, &b, 4);
  __hip_bfloat162 r = __hadd2(x, y);
  unsigned int u;
  __builtin_memcpy(&u, &r, 4);
  return u;
}

// ---- k0: transpose + bf16-ize weights: Wt[out][in] row-major ----
__global__ void prep_weights(const float* __restrict__ Wp, const float* __restrict__ Wc,
                             const float* __restrict__ W1, const float* __restrict__ W2,
                             short* __restrict__ wp_t, short* __restrict__ wc_t,
                             short* __restrict__ w1_t, float* __restrict__ w2v) {
  int i = blockIdx.x * 256 + threadIdx.x;
  if (i < HDIM * HDIM) {
    int o = i >> 7, k = i & (HDIM - 1);
    wp_t[i] = f2bf(Wp[k * HDIM + o]);
    wc_t[i] = f2bf(Wc[k * HDIM + o]);
  }
  if (i < HDIM * 3 * HDIM) {
    int o = i / (3 * HDIM), k = i - o * (3 * HDIM);
    w1_t[i] = f2bf(W1[k * HDIM + o]);
  }
  if (i < HDIM) w2v[i] = W2[i];
}

// ---- k1: per-node precompute into interleaved records ----
// 512 threads / 8 waves (full occupancy at 34.8 KB LDS); 2-buffer LDS reuse;
// coalesced rec writes via LDS staging. Wave w owns output cols w*16..w*16+15
// for BOTH small GEMMs of each phase.
__global__ __launch_bounds__(512, 8) void node_precompute(
    const float* __restrict__ x, const float* __restrict__ b_p,
    const float* __restrict__ b_c, const float* __restrict__ b1,
    const short* __restrict__ wp_t, const short* __restrict__ wc_t,
    const short* __restrict__ w1_t, short* __restrict__ rec) {
  __shared__ __align__(16) short Buf1[BM * LDP];  // Xt -> Yc -> B-stage
  __shared__ __align__(16) short Buf2[BM * LDP];  // Yp -> A-stage

  const int t = threadIdx.x;
  const int n0 = blockIdx.x * BM;
  const int lane16 = t & 15, rq = t >> 4, c0 = lane16 * 8;  // rq: 0..31

  // Phase A: stage x -> Buf1 (Xt); write x_bf part of rec (coalesced)
#pragma unroll
  for (int pass = 0; pass < 2; ++pass) {
    const int row = pass * 32 + rq;
    const int n = n0 + row;
    short8 v;
    if (n < N_NODES) {
      const float* ps = x + (size_t)n * HDIM + c0;
      float4 a = *(const float4*)ps;
      float4 b = *(const float4*)(ps + 4);
      float f[8] = {a.x, a.y, a.z, a.w, b.x, b.y, b.z, b.w};
#pragma unroll
      for (int j = 0; j < 8; ++j) v[j] = f2bf(f[j]);
      *(short8*)&rec[(size_t)n * REC + c0] = v;
    } else {
#pragma unroll
      for (int j = 0; j < 8; ++j) v[j] = 0;
    }
    *(short8*)&Buf1[row * LDP + c0] = v;
  }
  __syncthreads();

  const int l = t & 63;
  const int w = t >> 6;        // 0..7 -> cols w*16..w*16+15
  const int lr = l & 15;
  const int lg = l >> 4;
  const int aoff = lr * LDP + lg * 8;
  const int na = w * 16 + lr;  // this thread's output column (0..127)

  const f32x4 zero4 = {0.f, 0.f, 0.f, 0.f};
  f32x4 ap_[4], ac_[4];
#pragma unroll
  for (int mi = 0; mi < 4; ++mi) { ap_[mi] = zero4; ac_[mi] = zero4; }

  const short* wpA = wp_t + na * HDIM + lg * 8;
  const short* wcA = wc_t + na * HDIM + lg * 8;

  // Phase B: GEMM1 (X@Wp) + GEMM2 (X@Wc) from Buf1(Xt)
#pragma unroll
  for (int kk = 0; kk < 4; ++kk) {
    short8 bp8 = *(const short8*)(wpA + kk * 32);
    short8 bc8 = *(const short8*)(wcA + kk * 32);
#pragma unroll
    for (int mi = 0; mi < 4; ++mi) {
      short8 a8 = *(const short8*)&Buf1[mi * 16 * LDP + aoff + kk * 32];
      ap_[mi] = __builtin_amdgcn_mfma_f32_16x16x32_bf16(a8, bp8, ap_[mi], 0, 0, 0);
      ac_[mi] = __builtin_amdgcn_mfma_f32_16x16x32_bf16(a8, bc8, ac_[mi], 0, 0, 0);
    }
  }
  __syncthreads();  // Xt reads done; Buf1 reusable

  // lrelu+bias: Yp -> Buf2, Yc -> Buf1
  {
    const float bpa = b_p[na];
    const float bca = b_c[na];
#pragma unroll
    for (int mi = 0; mi < 4; ++mi) {
#pragma unroll
      for (int r = 0; r < 4; ++r) {
        const int m = mi * 16 + lg * 4 + r;
        float v0 = ap_[mi][r] + bpa; v0 = v0 > 0.f ? v0 : 0.01f * v0;
        float u0 = ac_[mi][r] + bca; u0 = u0 > 0.f ? u0 : 0.01f * u0;
        Buf2[m * LDP + na] = f2bf(v0);
        Buf1[m * LDP + na] = f2bf(u0);
      }
    }
  }
  __syncthreads();

  // Phase C: GEMM3a (Yp@W1a) + GEMM3b (Yc@W1b)
  f32x4 aa_[4], ab_[4];
#pragma unroll
  for (int mi = 0; mi < 4; ++mi) { aa_[mi] = zero4; ab_[mi] = zero4; }
  const short* w1Aa = w1_t + na * (3 * HDIM) + lg * 8;
#pragma unroll
  for (int kk = 0; kk < 4; ++kk) {
    short8 ba = *(const short8*)(w1Aa + kk * 32);
    short8 bb = *(const short8*)(w1Aa + HDIM + kk * 32);
#pragma unroll
    for (int mi = 0; mi < 4; ++mi) {
      short8 ayp = *(const short8*)&Buf2[mi * 16 * LDP + aoff + kk * 32];
      short8 ayc = *(const short8*)&Buf1[mi * 16 * LDP + aoff + kk * 32];
      aa_[mi] = __builtin_amdgcn_mfma_f32_16x16x32_bf16(ayp, ba, aa_[mi], 0, 0, 0);
      ab_[mi] = __builtin_amdgcn_mfma_f32_16x16x32_bf16(ayc, bb, ab_[mi], 0, 0, 0);
    }
  }
  __syncthreads();  // Yp/Yc reads done; buffers reusable

  // Stage A -> Buf2, B -> Buf1 as [node][col]
  {
    const float b1a = b1[na];
#pragma unroll
    for (int mi = 0; mi < 4; ++mi) {
#pragma unroll
      for (int r = 0; r < 4; ++r) {
        const int m = mi * 16 + lg * 4 + r;
        Buf2[m * LDP + na] = f2bf(aa_[mi][r] + b1a);
        Buf1[m * LDP + na] = f2bf(ab_[mi][r]);
      }
    }
  }
  __syncthreads();

  // Coalesced rec writes
#pragma unroll
  for (int pass = 0; pass < 2; ++pass) {
    const int row = pass * 32 + rq;
    const int n = n0 + row;
    if (n < N_NODES) {
      short* rn = rec + (size_t)n * REC;
      *(short8*)&rn[HDIM + c0] = *(const short8*)&Buf2[row * LDP + c0];
      *(short8*)&rn[2 * HDIM + c0] = *(const short8*)&Buf1[row * LDP + c0];
    }
  }
}

// ---- k2: per-edge (R9-validated structure, 136 us): swapped-operand MFMA,
// packed-bf16 staging, interleaved rec gathers, 1 tile/block ----
__global__ __launch_bounds__(512, 8) void edge_kernel(
    const int* __restrict__ ei, const short* __restrict__ rec,
    const short* __restrict__ w1_t, const float* __restrict__ w2v,
    const float* __restrict__ b2, float* __restrict__ out) {
  __shared__ __align__(16) short Dt[BM * LDP];   // 17408 B
  __shared__ __align__(16) short St[BM * LDP];   // 17408 B
  __shared__ float partial[8][BM];               // 2048 B

  const int t = threadIdx.x;
  const int e0 = blockIdx.x * BM;

  {
    const int lane16 = t & 15, rq = t >> 4, c0 = lane16 * 8;
#pragma unroll
    for (int pass = 0; pass < 2; ++pass) {
      const int row = pass * 32 + rq;
      const int s = ei[e0 + row];
      const int d = ei[E_EDGES + e0 + row];
      const short* rs = rec + (size_t)s * REC + c0;
      const short* rd = rec + (size_t)d * REC + c0;
      uint4 p = *(const uint4*)rs;                 // x_bf[s]
      uint4 a = *(const uint4*)(rs + HDIM);        // A[s]
      uint4 c = *(const uint4*)rd;                 // x_bf[d]
      uint4 b = *(const uint4*)(rd + 2 * HDIM);    // B[d]
      uint4 vd, vs;
      vd.x = bfsub_abs2(p.x, c.x);
      vd.y = bfsub_abs2(p.y, c.y);
      vd.z = bfsub_abs2(p.z, c.z);
      vd.w = bfsub_abs2(p.w, c.w);
      vs.x = bfadd2(a.x, b.x);
      vs.y = bfadd2(a.y, b.y);
      vs.z = bfadd2(a.z, b.z);
      vs.w = bfadd2(a.w, b.w);
      *(uint4*)&Dt[row * LDP + c0] = vd;
      *(uint4*)&St[row * LDP + c0] = vs;
    }
  }
  __syncthreads();

  const int l = t & 63;
  const int w = t >> 6;   // 0..7 -> cols w*16..w*16+15
  const int lr = l & 15;
  const int lg = l >> 4;
  const int aoff = lr * LDP + lg * 8;  // Dt fragment read (B operand: free=edge)

  // acc init = S^T: acc[mi][r] = S[edge = mi*16+lr][col = w*16+lg*4+r]
  f32x4 acc[4];
  const int scol = w * 16 + lg * 4;
#pragma unroll
  for (int mi = 0; mi < 4; ++mi) {
    uint2 u = *(const uint2*)&St[(mi * 16 + lr) * LDP + scol];
    acc[mi][0] = __uint_as_float(u.x << 16);
    acc[mi][1] = __uint_as_float(u.x & 0xffff0000u);
    acc[mi][2] = __uint_as_float(u.y << 16);
    acc[mi][3] = __uint_as_float(u.y & 0xffff0000u);
  }

  // GEMM (swapped): A-operand = W1c frag, B-operand = D frag -> acc = h^T
  const int na = w * 16 + lr;
  const short* w1D = w1_t + na * (3 * HDIM) + 2 * HDIM + lg * 8;
#pragma unroll
  for (int kk = 0; kk < 4; ++kk) {
    short8 b8 = *(const short8*)(w1D + kk * 32);
#pragma unroll
    for (int mi = 0; mi < 4; ++mi) {
      short8 a8 = *(const short8*)&Dt[mi * 16 * LDP + aoff + kk * 32];
      acc[mi] = __builtin_amdgcn_mfma_f32_16x16x32_bf16(b8, a8, acc[mi], 0, 0, 0);
    }
  }

  // epilogue: per-lane 4-col dot, 2-shfl reduce, per-wave partial
  {
    const float4 w2q = *(const float4*)&w2v[w * 16 + lg * 4];
#pragma unroll
    for (int mi = 0; mi < 4; ++mi) {
      float p = fmaxf(acc[mi][0], 0.f) * w2q.x + fmaxf(acc[mi][1], 0.f) * w2q.y +
                fmaxf(acc[mi][2], 0.f) * w2q.z + fmaxf(acc[mi][3], 0.f) * w2q.w;
      p += __shfl_xor(p, 16);
      p += __shfl_xor(p, 32);
      if (lg == 0) partial[w][mi * 16 + lr] = p;
    }
  }
  __syncthreads();

  if (t < BM) {
    float z = partial[0][t] + partial[1][t] + partial[2][t] + partial[3][t] +
              partial[4][t] + partial[5][t] + partial[6][t] + partial[7][t] + b2[0];
    out[e0 + t] = 1.0f / (1.0f + __expf(-z));
  }
}

// ---- fallback (validated v2 path) if workspace is too small ----
__global__ __launch_bounds__(512, 4) void edge_weight_fallback(
    const float* __restrict__ x, const int* __restrict__ ei,
    const float* __restrict__ b_p, const float* __restrict__ b_c,
    const float* __restrict__ b1, const float* __restrict__ b2,
    const short* __restrict__ wp_t, const short* __restrict__ wc_t,
    const short* __restrict__ w1_t, const float* __restrict__ w2v,
    float* __restrict__ out) {
  __shared__ __align__(16) short Pt[BM * LDP];
  __shared__ __align__(16) short Ct[BM * LDP];
  __shared__ __align__(16) short Dt[BM * LDP];
  __shared__ float partial[8][BM];

  const int t = threadIdx.x;
  const int e0 = blockIdx.x * BM;
  {
    const int lane16 = t & 15, rq = t >> 4, c0 = lane16 * 8;
#pragma unroll
    for (int pass = 0; pass < 2; ++pass) {
      const int row = pass * 32 + rq;
      const int ip = ei[e0 + row];
      const int ic = ei[E_EDGES + e0 + row];
      const float* ps = x + (size_t)ip * HDIM + c0;
      const float* cs = x + (size_t)ic * HDIM + c0;
      float4 pa = *(const float4*)ps, pb = *(const float4*)(ps + 4);
      float4 ca = *(const float4*)cs, cb = *(const float4*)(cs + 4);
      float pf[8] = {pa.x, pa.y, pa.z, pa.w, pb.x, pb.y, pb.z, pb.w};
      float cf[8] = {ca.x, ca.y, ca.z, ca.w, cb.x, cb.y, cb.z, cb.w};
      short8 vp, vc, vd;
#pragma unroll
      for (int j = 0; j < 8; ++j) {
        vp[j] = f2bf(pf[j]); vc[j] = f2bf(cf[j]); vd[j] = f2bf(fabsf(pf[j] - cf[j]));
      }
      *(short8*)&Pt[row * LDP + c0] = vp;
      *(short8*)&Ct[row * LDP + c0] = vc;
      *(short8*)&Dt[row * LDP + c0] = vd;
    }
  }
  __syncthreads();
  const int l = t & 63, w = t >> 6, lr = l & 15, lg = l >> 4;
  const int n0 = w * 16, na = n0 + lr, aoff = lr * LDP + lg * 8;
  const f32x4 zero4 = {0.f, 0.f, 0.f, 0.f};
  f32x4 acc1[4], acc2[4], acc3[4];
#pragma unroll
  for (int mi = 0; mi < 4; ++mi) { acc1[mi] = zero4; acc2[mi] = zero4; acc3[mi] = zero4; }
  const short* wpA = wp_t + na * HDIM + lg * 8;
  const short* wcA = wc_t + na * HDIM + lg * 8;
  const short* w1A = w1_t + na * (3 * HDIM) + lg * 8;
#pragma unroll
  for (int kk = 0; kk < 4; ++kk) {
    short8 bp8 = *(const short8*)(wpA + kk * 32);
    short8 bc8 = *(const short8*)(wcA + kk * 32);
    short8 bd8 = *(const short8*)(w1A + 2 * HDIM + kk * 32);
#pragma unroll
    for (int mi = 0; mi < 4; ++mi) {
      short8 ap = *(const short8*)&Pt[mi * 16 * LDP + aoff + kk * 32];
      short8 ac = *(const short8*)&Ct[mi * 16 * LDP + aoff + kk * 32];
      short8 ad = *(const short8*)&Dt[mi * 16 * LDP + aoff + kk * 32];
      acc1[mi] = __builtin_amdgcn_mfma_f32_16x16x32_bf16(ap, bp8, acc1[mi], 0, 0, 0);
      acc2[mi] = __builtin_amdgcn_mfma_f32_16x16x32_bf16(ac, bc8, acc2[mi], 0, 0, 0);
      acc3[mi] = __builtin_amdgcn_mfma_f32_16x16x32_bf16(ad, bd8, acc3[mi], 0, 0, 0);
    }
  }
  __syncthreads();
  {
    const float bpa = b_p[na], bca = b_c[na];
#pragma unroll
    for (int mi = 0; mi < 4; ++mi) {
#pragma unroll
      for (int r = 0; r < 4; ++r) {
        const int m = mi * 16 + lg * 4 + r;
        float v0 = acc1[mi][r] + bpa; v0 = v0 > 0.f ? v0 : 0.01f * v0;
        float u0 = acc2[mi][r] + bca; u0 = u0 > 0.f ? u0 : 0.01f * u0;
        Pt[m * LDP + na] = f2bf(v0);
        Ct[m * LDP + na] = f2bf(u0);
      }
    }
  }
  __syncthreads();
#pragma unroll
  for (int kk = 0; kk < 4; ++kk) {
    short8 b0 = *(const short8*)(w1A + kk * 32);
    short8 b1f = *(const short8*)(w1A + HDIM + kk * 32);
#pragma unroll
    for (int mi = 0; mi < 4; ++mi) {
      short8 a0 = *(const short8*)&Pt[mi * 16 * LDP + aoff + kk * 32];
      short8 a1 = *(const short8*)&Ct[mi * 16 * LDP + aoff + kk * 32];
      acc3[mi] = __builtin_amdgcn_mfma_f32_16x16x32_bf16(a0, b0, acc3[mi], 0, 0, 0);
      acc3[mi] = __builtin_amdgcn_mfma_f32_16x16x32_bf16(a1, b1f, acc3[mi], 0, 0, 0);
    }
  }
  {
    const float b1a = b1[na], w2a = w2v[na];
#pragma unroll
    for (int mi = 0; mi < 4; ++mi) {
#pragma unroll
      for (int r = 0; r < 4; ++r) {
        float h0 = acc3[mi][r] + b1a; h0 = h0 > 0.f ? h0 : 0.f;
        float v = h0 * w2a;
        v += __shfl_xor(v, 1); v += __shfl_xor(v, 2);
        v += __shfl_xor(v, 4); v += __shfl_xor(v, 8);
        if (lr == 0) partial[w][mi * 16 + lg * 4 + r] = v;
      }
    }
  }
  __syncthreads();
  if (t < BM) {
    float z = partial[0][t] + partial[1][t] + partial[2][t] + partial[3][t] +
              partial[4][t] + partial[5][t] + partial[6][t] + partial[7][t] + b2[0];
    out[e0 + t] = 1.0f / (1.0f + __expf(-z));
  }
}

extern "C" void kernel_launch(void* const* d_in, const int* in_sizes, int n_in,
                              void* d_out, int out_size, void* d_ws, size_t ws_size,
                              hipStream_t stream) {
  const float* x  = (const float*)d_in[0];
  const int*   ei = (const int*)d_in[1];
  const float* Wp = (const float*)d_in[2];
  const float* bp = (const float*)d_in[3];
  const float* Wc = (const float*)d_in[4];
  const float* bc = (const float*)d_in[5];
  const float* W1 = (const float*)d_in[6];
  const float* b1 = (const float*)d_in[7];
  const float* W2 = (const float*)d_in[8];
  const float* b2 = (const float*)d_in[9];
  float* out = (float*)d_out;

  short* wp_t = (short*)d_ws;
  short* wc_t = wp_t + HDIM * HDIM;
  short* w1_t = wc_t + HDIM * HDIM;
  float* w2v  = (float*)(w1_t + HDIM * 3 * HDIM);
  short* rec  = (short*)(w2v + HDIM);

  const size_t needed = (size_t)((char*)(rec + (size_t)N_NODES * REC) - (char*)d_ws);
  const int ntiles = E_EDGES / BM;

  prep_weights<<<(HDIM * 3 * HDIM + 255) / 256, 256, 0, stream>>>(Wp, Wc, W1, W2,
                                                                  wp_t, wc_t, w1_t, w2v);
  if (ws_size >= needed) {
    node_precompute<<<(N_NODES + BM - 1) / BM, 512, 0, stream>>>(
        x, bp, bc, b1, wp_t, wc_t, w1_t, rec);
    edge_kernel<<<ntiles, 512, 0, stream>>>(ei, rec, w1_t, w2v, b2, out);
  } else {
    edge_weight_fallback<<<ntiles, 512, 0, stream>>>(x, ei, bp, bc, b1, b2,
                                                     wp_t, wc_t, w1_t, w2v, out);
  }
}